// Round 8
// baseline (490.884 us; speedup 1.0000x reference)
//
#include <hip/hip_runtime.h>
#include <stdint.h>

#define N_NODES 10000
#define N_EDGES 160000
#define E_TOT   170000   // edges + self loops
#define IN_CH   1030
#define HC      1024
#define OUT_CH  49
#define NEG_SLOPE 0.2f
#define LN_EPS 1e-5f
#define LOG2E 1.4426950408889634f

#define MPAD  10112   // 79 * 128
#define K1PAD 1088    // 17 * 64 (1030 padded to BK=64 multiple)

typedef __attribute__((ext_vector_type(8))) __bf16 bf16x8;
typedef __attribute__((ext_vector_type(4))) float floatx4;
typedef __attribute__((ext_vector_type(2))) float floatx2;
typedef _Float16 h2 __attribute__((ext_vector_type(2)));

static __device__ __forceinline__ unsigned short f2bf(float f) {
  union { float f; uint32_t u; } v; v.f = f;
  uint32_t u = v.u;
  u += 0x7fffu + ((u >> 16) & 1u);   // round-to-nearest-even
  return (unsigned short)(u >> 16);
}
static __device__ __forceinline__ unsigned short f2h(float f) {
  _Float16 h = (_Float16)f;
  union { _Float16 h; unsigned short u; } v; v.h = h; return v.u;
}
static __device__ __forceinline__ h2 bits2h2(uint32_t u) {
  union { uint32_t i; h2 h; } v; v.i = u; return v.h;
}
static __device__ __forceinline__ floatx2 h2f2(h2 a) {
  floatx2 r; r.x = (float)a.x; r.y = (float)a.y; return r;
}

// wave64 sum-reduce on the VALU pipe: 4x row_shr + 2x row_bcast DPP adds,
// then readlane 63 -> wave-uniform scalar (SGPR). Zero LDS round-trips.
static __device__ __forceinline__ float wred_add(float x) {
#define DPP_ADD(ctrl, rmask)                                                   \
  x += __builtin_bit_cast(float, __builtin_amdgcn_update_dpp(                  \
           0, __builtin_bit_cast(int, x), ctrl, rmask, 0xf, true))
  DPP_ADD(0x111, 0xf);   // row_shr:1
  DPP_ADD(0x112, 0xf);   // row_shr:2
  DPP_ADD(0x114, 0xf);   // row_shr:4
  DPP_ADD(0x118, 0xf);   // row_shr:8  -> lane15 of each row16 = row sum
  DPP_ADD(0x142, 0xa);   // row_bcast:15 into rows 1,3
  DPP_ADD(0x143, 0xc);   // row_bcast:31 into rows 2,3 -> lane63 = total
#undef DPP_ADD
  return __builtin_bit_cast(float,
      __builtin_amdgcn_readlane(__builtin_bit_cast(int, x), 63));
}

// ---------------- casts ----------------

__global__ void cast_x_kernel(const float* __restrict__ x, unsigned short* __restrict__ xa,
                              int* __restrict__ counts) {
  int idx = blockIdx.x * 256 + threadIdx.x;       // over N_NODES * K1PAD
  if (idx < N_NODES) counts[idx] = 0;             // replaces memset
  if (idx >= N_NODES * K1PAD) return;
  int m = idx / K1PAD, k = idx - m * K1PAD;
  float v = (k < IN_CH) ? x[m * IN_CH + k] : 0.f;
  xa[idx] = f2bf(v);
}

// out[n*Kout + k] = (k < Kvalid ? W[k][n] : 0); W col picked from wa/wb by split
static __device__ __forceinline__ void transpose_body(
    float (*tile)[33], const float* __restrict__ wa, const float* __restrict__ wb,
    int split, int lda, int ldb, int Kvalid, int Kout,
    unsigned short* __restrict__ out, int bx, int by, int t) {
  int n0 = bx * 32, k0 = by * 32;
  int tx = t & 31, ty = t >> 5;  // 32 x 8
#pragma unroll
  for (int i = 0; i < 4; i++) {
    int k = k0 + ty + i * 8;
    int n = n0 + tx;
    float v = 0.f;
    if (k < Kvalid) v = (n < split) ? wa[(size_t)k * lda + n] : wb[(size_t)k * ldb + (n - split)];
    tile[ty + i * 8][tx] = v;
  }
  __syncthreads();
#pragma unroll
  for (int i = 0; i < 4; i++) {
    int n = n0 + ty + i * 8;
    int k = k0 + tx;
    out[(size_t)n * Kout + k] = f2bf(tile[tx][ty + i * 8]);
  }
}

// mega prep kernel: 3 weight transposes + edge count, one launch.
// counts zeroed by cast_x (previous dispatch on the stream).
#define NB_W1 2176   // 64 x 34
#define NB_W2 2048   // 64 x 32
#define NB_WC 256    // 8 x 32
#define NB_CNT 665   // ceil(E_TOT/256)
__global__ __launch_bounds__(256) void prep2_kernel(
    const float* __restrict__ c1_wl, const float* __restrict__ c1_wr,
    const float* __restrict__ c2_wl, const float* __restrict__ c2_wr,
    const float* __restrict__ cls_w1,
    const int* __restrict__ dstArr, int* __restrict__ counts,
    unsigned short* __restrict__ wt1, unsigned short* __restrict__ wt2,
    unsigned short* __restrict__ wtc1)
{
  __shared__ float tile[32][33];
  int b = blockIdx.x, t = threadIdx.x;
  if (b < NB_W1) {
    transpose_body(tile, c1_wl, c1_wr, 1024, 1024, 1024, IN_CH, K1PAD, wt1, b & 63, b >> 6, t);
  } else if (b < NB_W1 + NB_W2) {
    int bb = b - NB_W1;
    transpose_body(tile, c2_wl, c2_wr, 1024, 1024, 1024, 1024, 1024, wt2, bb & 63, bb >> 6, t);
  } else if (b < NB_W1 + NB_W2 + NB_WC) {
    int bb = b - (NB_W1 + NB_W2);
    transpose_body(tile, cls_w1, cls_w1, 256, 256, 256, 1024, 1024, wtc1, bb & 7, bb >> 3, t);
  } else {
    int e = (b - (NB_W1 + NB_W2 + NB_WC)) * 256 + t;
    if (e < E_TOT) {
      int d = (e < N_EDGES) ? dstArr[e] : (e - N_EDGES);
      atomicAdd(&counts[d], 1);
    }
  }
}

// two-level exclusive scan, 256 threads, 40 elems/thread serial.
// writes rstart (persistent) and rwork (scratch copy consumed by scatter).
__global__ __launch_bounds__(256) void scan_kernel(const int* __restrict__ counts,
                                                   int* __restrict__ rstart,
                                                   int* __restrict__ rwork) {
  __shared__ int sm[256];
  int t = threadIdx.x;
  int b0 = t * 40;
  int b1 = b0 + 40; if (b1 > N_NODES) b1 = N_NODES; if (b0 > N_NODES) b0 = N_NODES;
  int s = 0;
  for (int i = b0; i < b1; i++) s += counts[i];
  sm[t] = s; __syncthreads();
  for (int st = 1; st < 256; st <<= 1) {
    int add = (t >= st) ? sm[t - st] : 0;
    __syncthreads();
    sm[t] += add;
    __syncthreads();
  }
  int run = sm[t] - s;   // exclusive prefix of this thread's chunk
  for (int i = b0; i < b1; i++) { rstart[i] = run; rwork[i] = run; run += counts[i]; }
  if (t == 255) rstart[N_NODES] = run;
}

__global__ void scatter_kernel(const int* __restrict__ srcArr, const int* __restrict__ dstArr,
                               int* __restrict__ rwork, int* __restrict__ csrsrc) {
  int e = blockIdx.x * 256 + threadIdx.x;
  if (e >= E_TOT) return;
  if (e < 16) csrsrc[E_TOT + e] = 0;    // zero the prefetch pad (gat_ln over-reads)
  int d, sv;
  if (e < N_EDGES) { d = dstArr[e]; sv = srcArr[e]; }
  else { d = e - N_EDGES; sv = d; }     // self loop: src == dst
  int pos = atomicAdd(&rwork[d], 1);    // absolute position (rwork starts at rstart)
  csrsrc[pos] = sv;
}

// ---------------- 128x256 phase-pipelined MFMA GEMM (MODE2: f16 -> [m][2048]) ----
// R18: counted-vmcnt schedule (T3+T4+T5). 512 thr = 8 waves (2M x 4N), per-wave
// 64x64 out. BK=64; 2 phases/K-tile, 16 MFMA/phase. LDS 96KB dbuf (A 128x64,
// B 256x64). Stages of K-tile t+1 issued during iter t; vmcnt NEVER drains to 0
// in steady state (per-wave 6 loads/tile; TOP vmcnt(1), MID vmcnt(3)).
// All ds_reads strictly after {own counted vmcnt -> s_barrier} pairs; lgkmcnt(0)
// + sched_barrier(0) before MFMA per rule #18. Same XOR chunk-swizzle and
// fragment maps as the proven 128^2 kernel (0 bank conflicts).

extern __shared__ unsigned short smem256[];

template <int KC>
__global__ __launch_bounds__(512, 2) void gemm256(
    const unsigned short* __restrict__ A,    // [MPAD][KC]
    const unsigned short* __restrict__ Bt,   // [2048][KC]
    unsigned short* __restrict__ Cb,         // f16 [MPAD][2048]
    const float* __restrict__ blo, const float* __restrict__ bhi)
{
  constexpr int NT = KC / 64;
  unsigned short* As = smem256;              // [2][128*64]
  unsigned short* Bs = smem256 + 2 * 8192;   // [2][256*64]

  const int tid = threadIdx.x;
  const int w = tid >> 6, lane = tid & 63;
  const int wm = w >> 2, wn = w & 3;

  // XCD-aware bijective remap (632 = 8*79 blocks)
  const unsigned int bid = blockIdx.y * gridDim.x + blockIdx.x;
  const unsigned int wg = (bid & 7) * 79u + (bid >> 3);
  const int tile_n = (int)(wg % 8u) * 256;
  const int tile_m = (int)(wg / 8u) * 128;

  // staging geometry: per stage-slot (8KB), thread covers row rq, 16B chunk
  const int rq = tid >> 3;                       // 0..63
  const int gc = (tid & 7) ^ (rq & 7);           // swizzled source chunk
  const unsigned short* gA = A  + (size_t)(tile_m + rq) * KC + gc * 8;
  const unsigned short* gB = Bt + (size_t)(tile_n + rq) * KC + gc * 8;
  const int ldsw = w * 512;                      // wave-uniform LDS slot base

  const int lrow = lane & 15, cg0 = lane >> 4, sw = lrow & 7;

  floatx4 acc[4][4] = {};

#define STAGE_A(kt, p2)                                                          \
  __builtin_amdgcn_global_load_lds(                                              \
      (const __attribute__((address_space(1))) void*)(gA + (size_t)(p2) * 64 * KC + (kt) * 64), \
      (__attribute__((address_space(3))) void*)(As + ((kt) & 1) * 8192 + (p2) * 4096 + ldsw), 16, 0, 0)
#define STAGE_B(kt, s)                                                           \
  __builtin_amdgcn_global_load_lds(                                              \
      (const __attribute__((address_space(1))) void*)(gB + (size_t)(s) * 64 * KC + (kt) * 64),  \
      (__attribute__((address_space(3))) void*)(Bs + ((kt) & 1) * 16384 + (s) * 4096 + ldsw), 16, 0, 0)

  // prologue: tile 0; A1 issued LAST so TOP vmcnt(1) leaves exactly A1 in flight
  STAGE_B(0, 0); STAGE_B(0, 1); STAGE_A(0, 0);
  STAGE_B(0, 2); STAGE_B(0, 3); STAGE_A(0, 1);

  bf16x8 b[4][2], a[2][2];

#pragma unroll 1
  for (int t = 0; t < NT; ++t) {
    const unsigned short* Ac = As + (t & 1) * 8192;
    const unsigned short* Bc = Bs + (t & 1) * 16384;
    const bool st = (t + 1 < NT);

    // ---- TOP: own {B0..B3,A0}(t) landed -> block sync -> reads legal ----
    asm volatile("s_waitcnt vmcnt(1)" ::: "memory");
    __builtin_amdgcn_s_barrier();
    asm volatile("" ::: "memory");
    __builtin_amdgcn_sched_barrier(0);

    // ---- phase 0: all B-frags + A-frags 0,1 (rows 0..63) ----
#pragma unroll
    for (int n = 0; n < 4; ++n)
#pragma unroll
      for (int kh = 0; kh < 2; ++kh)
        b[n][kh] = *(const bf16x8*)(Bc + (wn * 64 + n * 16 + lrow) * 64 + (((kh << 2) | cg0) ^ sw) * 8);
#pragma unroll
    for (int f = 0; f < 2; ++f)
#pragma unroll
      for (int kh = 0; kh < 2; ++kh)
        a[f][kh] = *(const bf16x8*)(Ac + (f * 32 + wm * 16 + lrow) * 64 + (((kh << 2) | cg0) ^ sw) * 8);
    if (st) { STAGE_B(t + 1, 0); STAGE_B(t + 1, 1); STAGE_A(t + 1, 0); }
    __builtin_amdgcn_s_barrier();
    asm volatile("s_waitcnt lgkmcnt(0)" ::: "memory");
    __builtin_amdgcn_sched_barrier(0);
    __builtin_amdgcn_s_setprio(1);
#pragma unroll
    for (int f = 0; f < 2; ++f)
#pragma unroll
      for (int n = 0; n < 4; ++n) {
        acc[f][n] = __builtin_amdgcn_mfma_f32_16x16x32_bf16(a[f][0], b[n][0], acc[f][n], 0, 0, 0);
        acc[f][n] = __builtin_amdgcn_mfma_f32_16x16x32_bf16(a[f][1], b[n][1], acc[f][n], 0, 0, 0);
      }
    __builtin_amdgcn_s_setprio(0);

    // ---- MID: own A1(t) landed -> block sync ----
    if (st) asm volatile("s_waitcnt vmcnt(3)" ::: "memory");
    else    asm volatile("s_waitcnt vmcnt(0)" ::: "memory");
    __builtin_amdgcn_s_barrier();
    asm volatile("" ::: "memory");
    __builtin_amdgcn_sched_barrier(0);

    // ---- phase 1: A-frags 2,3 (rows 64..127) ----
#pragma unroll
    for (int f = 0; f < 2; ++f)
#pragma unroll
      for (int kh = 0; kh < 2; ++kh)
        a[f][kh] = *(const bf16x8*)(Ac + ((f + 2) * 32 + wm * 16 + lrow) * 64 + (((kh << 2) | cg0) ^ sw) * 8);
    if (st) { STAGE_B(t + 1, 2); STAGE_B(t + 1, 3); STAGE_A(t + 1, 1); }
    __builtin_amdgcn_s_barrier();
    asm volatile("s_waitcnt lgkmcnt(0)" ::: "memory");
    __builtin_amdgcn_sched_barrier(0);
    __builtin_amdgcn_s_setprio(1);
#pragma unroll
    for (int f = 0; f < 2; ++f)
#pragma unroll
      for (int n = 0; n < 4; ++n) {
        acc[f + 2][n] = __builtin_amdgcn_mfma_f32_16x16x32_bf16(a[f][0], b[n][0], acc[f + 2][n], 0, 0, 0);
        acc[f + 2][n] = __builtin_amdgcn_mfma_f32_16x16x32_bf16(a[f][1], b[n][1], acc[f + 2][n], 0, 0, 0);
      }
    __builtin_amdgcn_s_setprio(0);
  }
#undef STAGE_A
#undef STAGE_B

  // ---- epilogue: f16 store to [m][2048] with hoisted bias ----
  const int rbase = cg0 * 4;
  float bcol[4];
#pragma unroll
  for (int n = 0; n < 4; ++n) {
    int col = tile_n + wn * 64 + n * 16 + lrow;
    bcol[n] = (col < 1024) ? blo[col] : bhi[col - 1024];
  }
#pragma unroll
  for (int f = 0; f < 4; ++f) {
    const int mrow = tile_m + f * 32 + wm * 16 + rbase;
#pragma unroll
    for (int r = 0; r < 4; ++r) {
#pragma unroll
      for (int n = 0; n < 4; ++n) {
        int col = tile_n + wn * 64 + n * 16 + lrow;
        Cb[(size_t)(mrow + r) * 2048 + col] = f2h(acc[f][n][r] + bcol[n]);
      }
    }
  }
}

// ---------------- bf16 MFMA GEMM: 128x128 tile (kept for the small cls GEMM) ----
template <int MODE, int KC>
__global__ __launch_bounds__(256, 4) void gemm_bf16(
    const unsigned short* __restrict__ A, const unsigned short* __restrict__ Bt,
    float* __restrict__ Cf, unsigned short* __restrict__ Cb,
    const float* __restrict__ blo, const float* __restrict__ bhi,
    int M, int ldc, int bsplit)
{
  __shared__ __align__(16) unsigned short As[128 * 64];
  __shared__ __align__(16) unsigned short Bs[128 * 64];
  const int t = threadIdx.x;
  const int w = t >> 6, lane = t & 63;

  // XCD-aware bijective remap of the flattened block id
  const unsigned int nwg = gridDim.x * gridDim.y;
  const unsigned int bid = blockIdx.y * gridDim.x + blockIdx.x;
  const unsigned int q8 = nwg >> 3, r8 = nwg & 7;
  const unsigned int xcd = bid & 7, sub = bid >> 3;
  const unsigned int wg = (xcd < r8 ? xcd * (q8 + 1) : r8 * (q8 + 1) + (xcd - r8) * q8) + sub;
  const int tile_n = (wg % gridDim.x) * 128, tile_m = (wg / gridDim.x) * 128;

  floatx4 acc[4][4] = {};

  const int qq = w * 64 + lane;
  const int row0 = qq >> 3;
  const int gj = (qq & 7) ^ (row0 & 7);
  const unsigned short* gA0 = A  + (size_t)(tile_m + row0) * KC + gj * 8;
  const unsigned short* gB0 = Bt + (size_t)(tile_n + row0) * KC + gj * 8;

  const int wm = (w >> 1) * 64, wn = (w & 1) * 64;
  const int lrow = lane & 15, cg0 = (lane >> 4);
  const int sw = lrow & 7;

#pragma unroll 1
  for (int k0 = 0; k0 < KC; k0 += 64) {
#pragma unroll
    for (int p = 0; p < 4; p++) {
      __builtin_amdgcn_global_load_lds(
          (const __attribute__((address_space(1))) void*)(gA0 + p * 32 * KC),
          (__attribute__((address_space(3))) void*)(As + p * 2048 + w * 512), 16, 0, 0);
      __builtin_amdgcn_global_load_lds(
          (const __attribute__((address_space(1))) void*)(gB0 + p * 32 * KC),
          (__attribute__((address_space(3))) void*)(Bs + p * 2048 + w * 512), 16, 0, 0);
    }
    gA0 += 64; gB0 += 64;
    __syncthreads();
#pragma unroll
    for (int h = 0; h < 2; h++) {
      const int sc = (h * 4 + cg0) ^ sw;
      bf16x8 a[4], b[4];
#pragma unroll
      for (int mi = 0; mi < 4; mi++)
        a[mi] = *(const bf16x8*)(As + (wm + mi * 16 + lrow) * 64 + sc * 8);
#pragma unroll
      for (int ni = 0; ni < 4; ni++)
        b[ni] = *(const bf16x8*)(Bs + (wn + ni * 16 + lrow) * 64 + sc * 8);
#pragma unroll
      for (int mi = 0; mi < 4; mi++)
#pragma unroll
        for (int ni = 0; ni < 4; ni++)
          acc[mi][ni] = __builtin_amdgcn_mfma_f32_16x16x32_bf16(a[mi], b[ni], acc[mi][ni], 0, 0, 0);
    }
    __syncthreads();
  }

  float bcol[4];
#pragma unroll
  for (int ni = 0; ni < 4; ni++) {
    int n = tile_n + wn + ni * 16 + lrow;
    bcol[ni] = (n < bsplit) ? blo[n] : bhi[n - bsplit];
  }

  const int rbase = (lane >> 4) * 4;
#pragma unroll
  for (int mi = 0; mi < 4; mi++) {
#pragma unroll
    for (int r = 0; r < 4; r++) {
      int m = tile_m + wm + mi * 16 + rbase + r;
      if (m >= M) continue;
#pragma unroll
      for (int ni = 0; ni < 4; ni++) {
        int n = tile_n + wn + ni * 16 + lrow;
        float v = acc[mi][ni][r] + bcol[ni];
        if (MODE == 0) {
          Cf[(size_t)m * ldc + n] = v;
        } else if (MODE == 1) {
          Cf[(size_t)m * ldc + n] = v > 0.f ? v : expm1f(v);
        } else {
          Cb[(size_t)m * 2048 + n] = f2h(v);
        }
      }
    }
  }
}

// ---------------- fused GATv2 edge phase + LayerNorm + ELU -> bf16 -------------
// R3-verified structure: 4 ch/lane, wave==head, 4-edge unroll, 1-deep software
// pipeline, DPP wave reduce, scalar tail. Structural floor ~70 us (6 variants).

__global__ __launch_bounds__(256) void gat_ln_kernel(
    const unsigned short* __restrict__ xlr,  // [N,2048] f16: xl cols 0..1023, xr 1024..2047
    const float* __restrict__ att,           // [4,256] fp32
    const int* __restrict__ csrsrc, const int* __restrict__ rstart,
    const float* __restrict__ bias,
    const float* __restrict__ lnw, const float* __restrict__ lnb,
    unsigned short* __restrict__ out)        // [N,1024] bf16
{
  const int d = blockIdx.x;
  const int t = threadIdx.x;
  const int lane = t & 63, wv = t >> 6;
  const int c = wv * 256 + lane * 4;   // 4 channels of head wv

  uint2 xru = *(const uint2*)(xlr + (size_t)d * 2048 + 1024 + c);
  h2 xr0 = bits2h2(xru.x), xr1 = bits2h2(xru.y);
  float4 aw4 = *(const float4*)(att + c);
  h2 aw0, aw1;   // att * log2e in f16 (scores move to log2 domain)
  aw0.x = (_Float16)(aw4.x * LOG2E); aw0.y = (_Float16)(aw4.y * LOG2E);
  aw1.x = (_Float16)(aw4.z * LOG2E); aw1.y = (_Float16)(aw4.w * LOG2E);
  const h2 ns = {(_Float16)NEG_SLOPE, (_Float16)NEG_SLOPE};
  const unsigned short* xbase = xlr + c;

  int start = rstart[d], deg = rstart[d + 1] - start;

  float m = -3.0e38f, l = 0.f;
  floatx2 accA = {0.f, 0.f}, accB = {0.f, 0.f};

  int i = 0;
  if (deg >= 4) {
    int sA0 = csrsrc[start],     sA1 = csrsrc[start + 1];
    int sA2 = csrsrc[start + 2], sA3 = csrsrc[start + 3];
    uint2 uA0 = *(const uint2*)(xbase + (size_t)sA0 * 2048);
    uint2 uA1 = *(const uint2*)(xbase + (size_t)sA1 * 2048);
    uint2 uA2 = *(const uint2*)(xbase + (size_t)sA2 * 2048);
    uint2 uA3 = *(const uint2*)(xbase + (size_t)sA3 * 2048);
    int sB0 = csrsrc[start + 4], sB1 = csrsrc[start + 5];
    int sB2 = csrsrc[start + 6], sB3 = csrsrc[start + 7];
    for (; i + 4 <= deg; i += 4) {
      int sC0 = csrsrc[start + i + 8],  sC1 = csrsrc[start + i + 9];
      int sC2 = csrsrc[start + i + 10], sC3 = csrsrc[start + i + 11];
      uint2 uB0 = *(const uint2*)(xbase + (size_t)sB0 * 2048);
      uint2 uB1 = *(const uint2*)(xbase + (size_t)sB1 * 2048);
      uint2 uB2 = *(const uint2*)(xbase + (size_t)sB2 * 2048);
      uint2 uB3 = *(const uint2*)(xbase + (size_t)sB3 * 2048);

      h2 xh0a = bits2h2(uA0.x), xh0b = bits2h2(uA0.y);
      h2 xh1a = bits2h2(uA1.x), xh1b = bits2h2(uA1.y);
      h2 xh2a = bits2h2(uA2.x), xh2b = bits2h2(uA2.y);
      h2 xh3a = bits2h2(uA3.x), xh3b = bits2h2(uA3.y);
      h2 t0a = xh0a + xr0, t0b = xh0b + xr1;
      h2 t1a = xh1a + xr0, t1b = xh1b + xr1;
      h2 t2a = xh2a + xr0, t2b = xh2b + xr1;
      h2 t3a = xh3a + xr0, t3b = xh3b + xr1;
      h2 r0a = __builtin_elementwise_max(t0a, t0a * ns);
      h2 r0b = __builtin_elementwise_max(t0b, t0b * ns);
      h2 r1a = __builtin_elementwise_max(t1a, t1a * ns);
      h2 r1b = __builtin_elementwise_max(t1b, t1b * ns);
      h2 r2a = __builtin_elementwise_max(t2a, t2a * ns);
      h2 r2b = __builtin_elementwise_max(t2b, t2b * ns);
      h2 r3a = __builtin_elementwise_max(t3a, t3a * ns);
      h2 r3b = __builtin_elementwise_max(t3b, t3b * ns);
      float p0 = __builtin_amdgcn_fdot2(r0b, aw1, __builtin_amdgcn_fdot2(r0a, aw0, 0.f, false), false);
      float p1 = __builtin_amdgcn_fdot2(r1b, aw1, __builtin_amdgcn_fdot2(r1a, aw0, 0.f, false), false);
      float p2 = __builtin_amdgcn_fdot2(r2b, aw1, __builtin_amdgcn_fdot2(r2a, aw0, 0.f, false), false);
      float p3 = __builtin_amdgcn_fdot2(r3b, aw1, __builtin_amdgcn_fdot2(r3a, aw0, 0.f, false), false);
      p0 = wred_add(p0);
      p1 = wred_add(p1);
      p2 = wred_add(p2);
      p3 = wred_add(p3);
      float mx = fmaxf(fmaxf(p0, p1), fmaxf(p2, p3));
      if (mx > m) {
        float sc = exp2f(m - mx);
        floatx2 scv; scv.x = sc; scv.y = sc;
        accA *= scv; accB *= scv; l *= sc;
        m = mx;
      }
      float pe0 = exp2f(p0 - m), pe1 = exp2f(p1 - m);
      float pe2 = exp2f(p2 - m), pe3 = exp2f(p3 - m);
      floatx2 x0A = h2f2(xh0a), x0B = h2f2(xh0b);
      floatx2 x1A = h2f2(xh1a), x1B = h2f2(xh1b);
      floatx2 x2A = h2f2(xh2a), x2B = h2f2(xh2b);
      floatx2 x3A = h2f2(xh3a), x3B = h2f2(xh3b);
      floatx2 v0; v0.x = pe0; v0.y = pe0;
      floatx2 v1; v1.x = pe1; v1.y = pe1;
      floatx2 v2; v2.x = pe2; v2.y = pe2;
      floatx2 v3; v3.x = pe3; v3.y = pe3;
      accA += x0A * v0; accA += x1A * v1; accA += x2A * v2; accA += x3A * v3;
      accB += x0B * v0; accB += x1B * v1; accB += x2B * v2; accB += x3B * v3;
      l += pe0 + pe1 + pe2 + pe3;

      uA0 = uB0; uA1 = uB1; uA2 = uB2; uA3 = uB3;
      sB0 = sC0; sB1 = sC1; sB2 = sC2; sB3 = sC3;
    }
  }
  for (; i < deg; i++) {
    int s0 = csrsrc[start + i];
    uint2 u0 = *(const uint2*)(xbase + (size_t)s0 * 2048);
    h2 xh0a = bits2h2(u0.x), xh0b = bits2h2(u0.y);
    h2 t0a = xh0a + xr0, t0b = xh0b + xr1;
    h2 r0a = __builtin_elementwise_max(t0a, t0a * ns);
    h2 r0b = __builtin_elementwise_max(t0b, t0b * ns);
    float p0 = __builtin_amdgcn_fdot2(r0b, aw1, __builtin_amdgcn_fdot2(r0a, aw0, 0.f, false), false);
    p0 = wred_add(p0);
    if (p0 > m) {
      float sc = exp2f(m - p0);
      floatx2 scv; scv.x = sc; scv.y = sc;
      accA *= scv; accB *= scv; l *= sc;
      m = p0;
    }
    float pe0 = exp2f(p0 - m);
    floatx2 x0A = h2f2(xh0a), x0B = h2f2(xh0b);
    floatx2 pe0v; pe0v.x = pe0; pe0v.y = pe0;
    accA += x0A * pe0v;
    accB += x0B * pe0v;
    l += pe0;
  }

  float rd = 1.f / (l + 1e-16f);
  float4 bv = *(const float4*)(bias + c);
  float o0 = accA.x * rd + bv.x, o1 = accA.y * rd + bv.y;
  float o2 = accB.x * rd + bv.z, o3 = accB.y * rd + bv.w;

  __shared__ float ws1[4], ws2[4];
  float s1 = o0 + o1 + o2 + o3;
  float s2 = o0 * o0 + o1 * o1 + o2 * o2 + o3 * o3;
#pragma unroll
  for (int mm = 32; mm >= 1; mm >>= 1) {
    s1 += __shfl_xor(s1, mm, 64);
    s2 += __shfl_xor(s2, mm, 64);
  }
  if (lane == 0) { ws1[wv] = s1; ws2[wv] = s2; }
  __syncthreads();
  float mean = (ws1[0] + ws1[1] + ws1[2] + ws1[3]) * (1.f / 1024.f);
  float var  = (ws2[0] + ws2[1] + ws2[2] + ws2[3]) * (1.f / 1024.f) - mean * mean;
  float rstd = rsqrtf(var + LN_EPS);
  float4 wv4 = *(const float4*)(lnw + c);
  float4 bb  = *(const float4*)(lnb + c);
  float z0 = (o0 - mean) * rstd * wv4.x + bb.x; z0 = z0 > 0.f ? z0 : expm1f(z0);
  float z1 = (o1 - mean) * rstd * wv4.y + bb.y; z1 = z1 > 0.f ? z1 : expm1f(z1);
  float z2 = (o2 - mean) * rstd * wv4.z + bb.z; z2 = z2 > 0.f ? z2 : expm1f(z2);
  float z3 = (o3 - mean) * rstd * wv4.w + bb.w; z3 = z3 > 0.f ? z3 : expm1f(z3);
  ushort4 u;
  u.x = f2bf(z0); u.y = f2bf(z1); u.z = f2bf(z2); u.w = f2bf(z3);
  *(ushort4*)(out + (size_t)d * 1024 + c) = u;
}

// ---------------- final tiny GEMM: out[node][49] = h3 . w2 + b2 ----------------
// 2500 blocks x 256 threads, 4 nodes/block (one wave per node).

__global__ __launch_bounds__(256) void cls2_kernel(
    const float* __restrict__ h3, const float* __restrict__ w2,
    const float* __restrict__ b2, float* __restrict__ out)
{
  __shared__ float row[4][256];
  int t = threadIdx.x, wv = t >> 6, lane = t & 63;
  int node = blockIdx.x * 4 + wv;
  *(float4*)(&row[wv][lane * 4]) = *(const float4*)(h3 + (size_t)node * 256 + lane * 4);
  __syncthreads();
  if (lane < OUT_CH) {
    float a0 = 0.f, a1 = 0.f, a2 = 0.f, a3 = 0.f;
#pragma unroll 4
    for (int k = 0; k < 256; k += 4) {
      a0 += row[wv][k]     * w2[(k    ) * OUT_CH + lane];
      a1 += row[wv][k + 1] * w2[(k + 1) * OUT_CH + lane];
      a2 += row[wv][k + 2] * w2[(k + 2) * OUT_CH + lane];
      a3 += row[wv][k + 3] * w2[(k + 3) * OUT_CH + lane];
    }
    out[node * OUT_CH + lane] = (a0 + a1) + (a2 + a3) + b2[lane];
  }
}

// ---------------- launch ----------------

extern "C" void kernel_launch(void* const* d_in, const int* in_sizes, int n_in,
                              void* d_out, int out_size, void* d_ws, size_t ws_size,
                              hipStream_t stream)
{
  const float* x       = (const float*)d_in[0];
  const int*   ei      = (const int*)d_in[1];
  const float* c1_wl   = (const float*)d_in[2];
  const float* c1_bl   = (const float*)d_in[3];
  const float* c1_wr   = (const float*)d_in[4];
  const float* c1_br   = (const float*)d_in[5];
  const float* c1_att  = (const float*)d_in[6];
  const float* c1_bias = (const float*)d_in[7];
  const float* ln1_w   = (const float*)d_in[8];
  const float* ln1_b   = (const float*)d_in[9];
  const float* c2_wl   = (const float*)d_in[10];
  const float* c2_bl   = (const float*)d_in[11];
  const float* c2_wr   = (const float*)d_in[12];
  const float* c2_br   = (const float*)d_in[13];
  const float* c2_att  = (const float*)d_in[14];
  const float* c2_bias = (const float*)d_in[15];
  const float* ln2_w   = (const float*)d_in[16];
  const float* ln2_b   = (const float*)d_in[17];
  const float* cls_w1  = (const float*)d_in[18];
  const float* cls_b1  = (const float*)d_in[19];
  const float* cls_w2  = (const float*)d_in[20];
  const float* cls_b2  = (const float*)d_in[21];

  const int* srcArr = ei;
  const int* dstArr = ei + N_EDGES;

  char* ws = (char*)d_ws;
  size_t off = 0;
  auto alloc = [&](size_t bytes) { void* p = ws + off; off += (bytes + 255) & ~(size_t)255; return p; };
  unsigned short* xa      = (unsigned short*)alloc((size_t)MPAD * K1PAD * 2);
  unsigned short* wt1     = (unsigned short*)alloc((size_t)2048 * K1PAD * 2);
  unsigned short* wt2     = (unsigned short*)alloc((size_t)2048 * 1024 * 2);
  unsigned short* wtc1    = (unsigned short*)alloc((size_t)256 * 1024 * 2);
  unsigned short* xlr     = (unsigned short*)alloc((size_t)MPAD * 2048 * 2);   // f16 xl|xr (pad rows written by gemm256)
  float*          h3      = (float*)alloc((size_t)N_NODES * 256 * 4);
  unsigned short* hb      = (unsigned short*)alloc((size_t)MPAD * 1024 * 2);
  int*            counts  = (int*)alloc(N_NODES * 4);
  int*            rwork   = (int*)alloc(N_NODES * 4);
  int*            rstart  = (int*)alloc((N_NODES + 1) * 4);
  int*            csrsrc  = (int*)alloc((E_TOT + 16) * 4);   // +16 prefetch pad
  (void)in_sizes; (void)n_in; (void)out_size; (void)ws_size;

  // prep (cast_x also zeroes counts — replaces memset)
  cast_x_kernel<<<(N_NODES * K1PAD + 255) / 256, 256, 0, stream>>>(x, xa, counts);
  prep2_kernel<<<NB_W1 + NB_W2 + NB_WC + NB_CNT, 256, 0, stream>>>(
      c1_wl, c1_wr, c2_wl, c2_wr, cls_w1, dstArr, counts, wt1, wt2, wtc1);

  // CSR by dst (payload = src node id)
  scan_kernel<<<1, 256, 0, stream>>>(counts, rstart, rwork);
  scatter_kernel<<<(E_TOT + 255) / 256, 256, 0, stream>>>(srcArr, dstArr, rwork, csrsrc);

  // layer 1
  gemm256<K1PAD><<<dim3(8, 79), 512, 98304, stream>>>(xa, wt1, xlr, c1_bl, c1_br);
  gat_ln_kernel<<<N_NODES, 256, 0, stream>>>(xlr, c1_att, csrsrc, rstart, c1_bias, ln1_w, ln1_b, hb);

  // layer 2
  gemm256<1024><<<dim3(8, 79), 512, 98304, stream>>>(hb, wt2, xlr, c2_bl, c2_br);
  gat_ln_kernel<<<N_NODES, 256, 0, stream>>>(xlr, c2_att, csrsrc, rstart, c2_bias, ln2_w, ln2_b, hb);

  // classifier
  gemm_bf16<1, 1024><<<dim3(2, 79), 256, 0, stream>>>(hb, wtc1, h3, nullptr, cls_b1, cls_b1, N_NODES, 256, 1024);
  cls2_kernel<<<2500, 256, 0, stream>>>(h3, cls_w2, cls_b2, (float*)d_out);
}

// Round 9
// 450.790 us; speedup vs baseline: 1.0889x; 1.0889x over previous
//
#include <hip/hip_runtime.h>
#include <stdint.h>

#define N_NODES 10000
#define N_EDGES 160000
#define E_TOT   170000   // edges + self loops
#define IN_CH   1030
#define HC      1024
#define OUT_CH  49
#define NEG_SLOPE 0.2f
#define LN_EPS 1e-5f
#define LOG2E 1.4426950408889634f

#define MPAD  10112   // 79 * 128
#define K1PAD 1088    // 17 * 64 (1030 padded to BK=64 multiple)

typedef __attribute__((ext_vector_type(8))) __bf16 bf16x8;
typedef __attribute__((ext_vector_type(8))) _Float16 h8;
typedef __attribute__((ext_vector_type(4))) float floatx4;
typedef __attribute__((ext_vector_type(2))) float floatx2;
typedef _Float16 h2 __attribute__((ext_vector_type(2)));

static __device__ __forceinline__ unsigned short f2bf(float f) {
  union { float f; uint32_t u; } v; v.f = f;
  uint32_t u = v.u;
  u += 0x7fffu + ((u >> 16) & 1u);   // round-to-nearest-even
  return (unsigned short)(u >> 16);
}
static __device__ __forceinline__ unsigned short f2h(float f) {
  _Float16 h = (_Float16)f;
  union { _Float16 h; unsigned short u; } v; v.h = h; return v.u;
}
static __device__ __forceinline__ h2 bits2h2(uint32_t u) {
  union { uint32_t i; h2 h; } v; v.i = u; return v.h;
}
static __device__ __forceinline__ floatx2 h2f2(h2 a) {
  floatx2 r; r.x = (float)a.x; r.y = (float)a.y; return r;
}

// wave64 sum-reduce on the VALU pipe: 4x row_shr + 2x row_bcast DPP adds,
// then readlane 63 -> wave-uniform scalar (SGPR). Zero LDS round-trips.
static __device__ __forceinline__ float wred_add(float x) {
#define DPP_ADD(ctrl, rmask)                                                   \
  x += __builtin_bit_cast(float, __builtin_amdgcn_update_dpp(                  \
           0, __builtin_bit_cast(int, x), ctrl, rmask, 0xf, true))
  DPP_ADD(0x111, 0xf);   // row_shr:1
  DPP_ADD(0x112, 0xf);   // row_shr:2
  DPP_ADD(0x114, 0xf);   // row_shr:4
  DPP_ADD(0x118, 0xf);   // row_shr:8  -> lane15 of each row16 = row sum
  DPP_ADD(0x142, 0xa);   // row_bcast:15 into rows 1,3
  DPP_ADD(0x143, 0xc);   // row_bcast:31 into rows 2,3 -> lane63 = total
#undef DPP_ADD
  return __builtin_bit_cast(float,
      __builtin_amdgcn_readlane(__builtin_bit_cast(int, x), 63));
}

// ---------------- casts ----------------
// R19: 4 outputs/thread; x row base m*1030+k is always even (both even) -> 8B
// aligned float2 loads. 10625 blocks vs 42500 scalar.

__global__ void cast_x_kernel(const float* __restrict__ x, unsigned short* __restrict__ xa,
                              int* __restrict__ counts) {
  int idx = blockIdx.x * 256 + threadIdx.x;       // over N_NODES * 272
  if (idx < N_NODES) counts[idx] = 0;             // replaces memset
  if (idx >= N_NODES * (K1PAD / 4)) return;
  int m = idx / (K1PAD / 4), k4 = idx - m * (K1PAD / 4);
  int k = k4 * 4;
  ushort4 o;
  if (k + 3 < IN_CH) {
    float2 v0 = *(const float2*)(x + (size_t)m * IN_CH + k);
    float2 v1 = *(const float2*)(x + (size_t)m * IN_CH + k + 2);
    o.x = f2bf(v0.x); o.y = f2bf(v0.y); o.z = f2bf(v1.x); o.w = f2bf(v1.y);
  } else {
    o.x = (k     < IN_CH) ? f2bf(x[(size_t)m * IN_CH + k    ]) : (unsigned short)0;
    o.y = (k + 1 < IN_CH) ? f2bf(x[(size_t)m * IN_CH + k + 1]) : (unsigned short)0;
    o.z = (k + 2 < IN_CH) ? f2bf(x[(size_t)m * IN_CH + k + 2]) : (unsigned short)0;
    o.w = (unsigned short)0;
  }
  *(ushort4*)(xa + (size_t)m * K1PAD + k) = o;
}

// out[n*Kout + k] = (k < Kvalid ? W[k][n] : 0); W col picked from wa/wb by split.
// ldb == 0 -> zero-fill for n >= split. f16o selects f16 vs bf16 output.
static __device__ __forceinline__ void transpose_body(
    float (*tile)[33], const float* __restrict__ wa, const float* __restrict__ wb,
    int split, int lda, int ldb, int Kvalid, int Kout,
    unsigned short* __restrict__ out, int bx, int by, int t, bool f16o) {
  int n0 = bx * 32, k0 = by * 32;
  int tx = t & 31, ty = t >> 5;  // 32 x 8
#pragma unroll
  for (int i = 0; i < 4; i++) {
    int k = k0 + ty + i * 8;
    int n = n0 + tx;
    float v = 0.f;
    if (k < Kvalid) {
      if (n < split) v = wa[(size_t)k * lda + n];
      else if (ldb)  v = wb[(size_t)k * ldb + (n - split)];
    }
    tile[ty + i * 8][tx] = v;
  }
  __syncthreads();
#pragma unroll
  for (int i = 0; i < 4; i++) {
    int n = n0 + ty + i * 8;
    int k = k0 + tx;
    float v = tile[tx][ty + i * 8];
    out[(size_t)n * Kout + k] = f16o ? f2h(v) : f2bf(v);
  }
}

// mega prep kernel: 4 weight transposes + edge count, one launch.
// counts zeroed by cast_x (previous dispatch on the stream).
#define NB_W1 2176   // 64 x 34
#define NB_W2 2048   // 64 x 32
#define NB_WC 256    // 8 x 32
#define NB_WC2 16    // 2 x 8 (cls_w2 -> f16 [64][256], zero-padded n>=49)
#define NB_CNT 665   // ceil(E_TOT/256)
__global__ __launch_bounds__(256) void prep2_kernel(
    const float* __restrict__ c1_wl, const float* __restrict__ c1_wr,
    const float* __restrict__ c2_wl, const float* __restrict__ c2_wr,
    const float* __restrict__ cls_w1, const float* __restrict__ cls_w2,
    const int* __restrict__ dstArr, int* __restrict__ counts,
    unsigned short* __restrict__ wt1, unsigned short* __restrict__ wt2,
    unsigned short* __restrict__ wtc1, unsigned short* __restrict__ wtc2)
{
  __shared__ float tile[32][33];
  int b = blockIdx.x, t = threadIdx.x;
  if (b < NB_W1) {
    transpose_body(tile, c1_wl, c1_wr, 1024, 1024, 1024, IN_CH, K1PAD, wt1, b & 63, b >> 6, t, false);
  } else if (b < NB_W1 + NB_W2) {
    int bb = b - NB_W1;
    transpose_body(tile, c2_wl, c2_wr, 1024, 1024, 1024, 1024, 1024, wt2, bb & 63, bb >> 6, t, false);
  } else if (b < NB_W1 + NB_W2 + NB_WC) {
    int bb = b - (NB_W1 + NB_W2);
    transpose_body(tile, cls_w1, cls_w1, 256, 256, 256, 1024, 1024, wtc1, bb & 7, bb >> 3, t, false);
  } else if (b < NB_W1 + NB_W2 + NB_WC + NB_WC2) {
    int bb = b - (NB_W1 + NB_W2 + NB_WC);
    transpose_body(tile, cls_w2, cls_w2, OUT_CH, OUT_CH, 0, 256, 256, wtc2, bb & 1, bb >> 1, t, true);
  } else {
    int e = (b - (NB_W1 + NB_W2 + NB_WC + NB_WC2)) * 256 + t;
    if (e < E_TOT) {
      int d = (e < N_EDGES) ? dstArr[e] : (e - N_EDGES);
      atomicAdd(&counts[d], 1);
    }
  }
}

// two-level exclusive scan, 256 threads, 40 elems/thread serial.
// writes rstart (persistent) and rwork (scratch copy consumed by scatter).
__global__ __launch_bounds__(256) void scan_kernel(const int* __restrict__ counts,
                                                   int* __restrict__ rstart,
                                                   int* __restrict__ rwork) {
  __shared__ int sm[256];
  int t = threadIdx.x;
  int b0 = t * 40;
  int b1 = b0 + 40; if (b1 > N_NODES) b1 = N_NODES; if (b0 > N_NODES) b0 = N_NODES;
  int s = 0;
  for (int i = b0; i < b1; i++) s += counts[i];
  sm[t] = s; __syncthreads();
  for (int st = 1; st < 256; st <<= 1) {
    int add = (t >= st) ? sm[t - st] : 0;
    __syncthreads();
    sm[t] += add;
    __syncthreads();
  }
  int run = sm[t] - s;   // exclusive prefix of this thread's chunk
  for (int i = b0; i < b1; i++) { rstart[i] = run; rwork[i] = run; run += counts[i]; }
  if (t == 255) rstart[N_NODES] = run;
}

__global__ void scatter_kernel(const int* __restrict__ srcArr, const int* __restrict__ dstArr,
                               int* __restrict__ rwork, int* __restrict__ csrsrc) {
  int e = blockIdx.x * 256 + threadIdx.x;
  if (e >= E_TOT) return;
  if (e < 16) csrsrc[E_TOT + e] = 0;    // zero the prefetch pad (gat_ln over-reads)
  int d, sv;
  if (e < N_EDGES) { d = dstArr[e]; sv = srcArr[e]; }
  else { d = e - N_EDGES; sv = d; }     // self loop: src == dst
  int pos = atomicAdd(&rwork[d], 1);    // absolute position (rwork starts at rstart)
  csrsrc[pos] = sv;
}

// ---------------- bf16 MFMA GEMM: 128x128 tile, BK=64, XOR-swizzled LDS ----------------
// R7-verified. MODE 2: all-FP16 -> Cb[m*2048+n] (xlr feeds only gat_ln).
// Bijective XCD swizzle (q/r chunked) keeps A-panel-sharing blocks on one XCD's L2.
template <int MODE, int KC>
__global__ __launch_bounds__(256, 4) void gemm_bf16(
    const unsigned short* __restrict__ A, const unsigned short* __restrict__ Bt,
    float* __restrict__ Cf, unsigned short* __restrict__ Cb,
    const float* __restrict__ blo, const float* __restrict__ bhi,
    int M, int ldc, int bsplit)
{
  __shared__ __align__(16) unsigned short As[128 * 64];
  __shared__ __align__(16) unsigned short Bs[128 * 64];
  const int t = threadIdx.x;
  const int w = t >> 6, lane = t & 63;

  // XCD-aware bijective remap of the flattened block id
  const unsigned int nwg = gridDim.x * gridDim.y;
  const unsigned int bid = blockIdx.y * gridDim.x + blockIdx.x;
  const unsigned int q8 = nwg >> 3, r8 = nwg & 7;
  const unsigned int xcd = bid & 7, sub = bid >> 3;
  const unsigned int wg = (xcd < r8 ? xcd * (q8 + 1) : r8 * (q8 + 1) + (xcd - r8) * q8) + sub;
  const int tile_n = (wg % gridDim.x) * 128, tile_m = (wg / gridDim.x) * 128;

  floatx4 acc[4][4] = {};

  const int qq = w * 64 + lane;
  const int row0 = qq >> 3;
  const int gj = (qq & 7) ^ (row0 & 7);
  const unsigned short* gA0 = A  + (size_t)(tile_m + row0) * KC + gj * 8;
  const unsigned short* gB0 = Bt + (size_t)(tile_n + row0) * KC + gj * 8;

  const int wm = (w >> 1) * 64, wn = (w & 1) * 64;
  const int lrow = lane & 15, cg0 = (lane >> 4);
  const int sw = lrow & 7;

#pragma unroll 1
  for (int k0 = 0; k0 < KC; k0 += 64) {
#pragma unroll
    for (int p = 0; p < 4; p++) {
      __builtin_amdgcn_global_load_lds(
          (const __attribute__((address_space(1))) void*)(gA0 + p * 32 * KC),
          (__attribute__((address_space(3))) void*)(As + p * 2048 + w * 512), 16, 0, 0);
      __builtin_amdgcn_global_load_lds(
          (const __attribute__((address_space(1))) void*)(gB0 + p * 32 * KC),
          (__attribute__((address_space(3))) void*)(Bs + p * 2048 + w * 512), 16, 0, 0);
    }
    gA0 += 64; gB0 += 64;
    __syncthreads();
#pragma unroll
    for (int h = 0; h < 2; h++) {
      const int sc = (h * 4 + cg0) ^ sw;
      bf16x8 a[4], b[4];
#pragma unroll
      for (int mi = 0; mi < 4; mi++)
        a[mi] = *(const bf16x8*)(As + (wm + mi * 16 + lrow) * 64 + sc * 8);
#pragma unroll
      for (int ni = 0; ni < 4; ni++)
        b[ni] = *(const bf16x8*)(Bs + (wn + ni * 16 + lrow) * 64 + sc * 8);
#pragma unroll
      for (int mi = 0; mi < 4; mi++)
#pragma unroll
        for (int ni = 0; ni < 4; ni++)
          acc[mi][ni] = __builtin_amdgcn_mfma_f32_16x16x32_bf16(a[mi], b[ni], acc[mi][ni], 0, 0, 0);
    }
    __syncthreads();
  }

  float bcol[4];
#pragma unroll
  for (int ni = 0; ni < 4; ni++) {
    int n = tile_n + wn + ni * 16 + lrow;
    bcol[ni] = (n < bsplit) ? blo[n] : bhi[n - bsplit];
  }

  const int rbase = (lane >> 4) * 4;
#pragma unroll
  for (int mi = 0; mi < 4; mi++) {
#pragma unroll
    for (int r = 0; r < 4; r++) {
      int m = tile_m + wm + mi * 16 + rbase + r;
      if (m >= M) continue;
#pragma unroll
      for (int ni = 0; ni < 4; ni++) {
        int n = tile_n + wn + ni * 16 + lrow;
        float v = acc[mi][ni][r] + bcol[ni];
        if (MODE == 0) {
          Cf[(size_t)m * ldc + n] = v;
        } else if (MODE == 1) {
          Cf[(size_t)m * ldc + n] = v > 0.f ? v : expm1f(v);
        } else {
          Cb[(size_t)m * 2048 + n] = f2h(v);
        }
      }
    }
  }
}

// ---------------- fused GATv2 edge phase + LayerNorm + ELU -> bf16 -------------
// R3-verified structure: 4 ch/lane, wave==head, 4-edge unroll, 1-deep software
// pipeline, DPP wave reduce, scalar tail. Structural floor ~70 us (6 variants).

__global__ __launch_bounds__(256) void gat_ln_kernel(
    const unsigned short* __restrict__ xlr,  // [N,2048] f16: xl cols 0..1023, xr 1024..2047
    const float* __restrict__ att,           // [4,256] fp32
    const int* __restrict__ csrsrc, const int* __restrict__ rstart,
    const float* __restrict__ bias,
    const float* __restrict__ lnw, const float* __restrict__ lnb,
    unsigned short* __restrict__ out)        // [N,1024] bf16
{
  const int d = blockIdx.x;
  const int t = threadIdx.x;
  const int lane = t & 63, wv = t >> 6;
  const int c = wv * 256 + lane * 4;   // 4 channels of head wv

  uint2 xru = *(const uint2*)(xlr + (size_t)d * 2048 + 1024 + c);
  h2 xr0 = bits2h2(xru.x), xr1 = bits2h2(xru.y);
  float4 aw4 = *(const float4*)(att + c);
  h2 aw0, aw1;   // att * log2e in f16 (scores move to log2 domain)
  aw0.x = (_Float16)(aw4.x * LOG2E); aw0.y = (_Float16)(aw4.y * LOG2E);
  aw1.x = (_Float16)(aw4.z * LOG2E); aw1.y = (_Float16)(aw4.w * LOG2E);
  const h2 ns = {(_Float16)NEG_SLOPE, (_Float16)NEG_SLOPE};
  const unsigned short* xbase = xlr + c;

  int start = rstart[d], deg = rstart[d + 1] - start;

  float m = -3.0e38f, l = 0.f;
  floatx2 accA = {0.f, 0.f}, accB = {0.f, 0.f};

  int i = 0;
  if (deg >= 4) {
    int sA0 = csrsrc[start],     sA1 = csrsrc[start + 1];
    int sA2 = csrsrc[start + 2], sA3 = csrsrc[start + 3];
    uint2 uA0 = *(const uint2*)(xbase + (size_t)sA0 * 2048);
    uint2 uA1 = *(const uint2*)(xbase + (size_t)sA1 * 2048);
    uint2 uA2 = *(const uint2*)(xbase + (size_t)sA2 * 2048);
    uint2 uA3 = *(const uint2*)(xbase + (size_t)sA3 * 2048);
    int sB0 = csrsrc[start + 4], sB1 = csrsrc[start + 5];
    int sB2 = csrsrc[start + 6], sB3 = csrsrc[start + 7];
    for (; i + 4 <= deg; i += 4) {
      int sC0 = csrsrc[start + i + 8],  sC1 = csrsrc[start + i + 9];
      int sC2 = csrsrc[start + i + 10], sC3 = csrsrc[start + i + 11];
      uint2 uB0 = *(const uint2*)(xbase + (size_t)sB0 * 2048);
      uint2 uB1 = *(const uint2*)(xbase + (size_t)sB1 * 2048);
      uint2 uB2 = *(const uint2*)(xbase + (size_t)sB2 * 2048);
      uint2 uB3 = *(const uint2*)(xbase + (size_t)sB3 * 2048);

      h2 xh0a = bits2h2(uA0.x), xh0b = bits2h2(uA0.y);
      h2 xh1a = bits2h2(uA1.x), xh1b = bits2h2(uA1.y);
      h2 xh2a = bits2h2(uA2.x), xh2b = bits2h2(uA2.y);
      h2 xh3a = bits2h2(uA3.x), xh3b = bits2h2(uA3.y);
      h2 t0a = xh0a + xr0, t0b = xh0b + xr1;
      h2 t1a = xh1a + xr0, t1b = xh1b + xr1;
      h2 t2a = xh2a + xr0, t2b = xh2b + xr1;
      h2 t3a = xh3a + xr0, t3b = xh3b + xr1;
      h2 r0a = __builtin_elementwise_max(t0a, t0a * ns);
      h2 r0b = __builtin_elementwise_max(t0b, t0b * ns);
      h2 r1a = __builtin_elementwise_max(t1a, t1a * ns);
      h2 r1b = __builtin_elementwise_max(t1b, t1b * ns);
      h2 r2a = __builtin_elementwise_max(t2a, t2a * ns);
      h2 r2b = __builtin_elementwise_max(t2b, t2b * ns);
      h2 r3a = __builtin_elementwise_max(t3a, t3a * ns);
      h2 r3b = __builtin_elementwise_max(t3b, t3b * ns);
      float p0 = __builtin_amdgcn_fdot2(r0b, aw1, __builtin_amdgcn_fdot2(r0a, aw0, 0.f, false), false);
      float p1 = __builtin_amdgcn_fdot2(r1b, aw1, __builtin_amdgcn_fdot2(r1a, aw0, 0.f, false), false);
      float p2 = __builtin_amdgcn_fdot2(r2b, aw1, __builtin_amdgcn_fdot2(r2a, aw0, 0.f, false), false);
      float p3 = __builtin_amdgcn_fdot2(r3b, aw1, __builtin_amdgcn_fdot2(r3a, aw0, 0.f, false), false);
      p0 = wred_add(p0);
      p1 = wred_add(p1);
      p2 = wred_add(p2);
      p3 = wred_add(p3);
      float mx = fmaxf(fmaxf(p0, p1), fmaxf(p2, p3));
      if (mx > m) {
        float sc = exp2f(m - mx);
        floatx2 scv; scv.x = sc; scv.y = sc;
        accA *= scv; accB *= scv; l *= sc;
        m = mx;
      }
      float pe0 = exp2f(p0 - m), pe1 = exp2f(p1 - m);
      float pe2 = exp2f(p2 - m), pe3 = exp2f(p3 - m);
      floatx2 x0A = h2f2(xh0a), x0B = h2f2(xh0b);
      floatx2 x1A = h2f2(xh1a), x1B = h2f2(xh1b);
      floatx2 x2A = h2f2(xh2a), x2B = h2f2(xh2b);
      floatx2 x3A = h2f2(xh3a), x3B = h2f2(xh3b);
      floatx2 v0; v0.x = pe0; v0.y = pe0;
      floatx2 v1; v1.x = pe1; v1.y = pe1;
      floatx2 v2; v2.x = pe2; v2.y = pe2;
      floatx2 v3; v3.x = pe3; v3.y = pe3;
      accA += x0A * v0; accA += x1A * v1; accA += x2A * v2; accA += x3A * v3;
      accB += x0B * v0; accB += x1B * v1; accB += x2B * v2; accB += x3B * v3;
      l += pe0 + pe1 + pe2 + pe3;

      uA0 = uB0; uA1 = uB1; uA2 = uB2; uA3 = uB3;
      sB0 = sC0; sB1 = sC1; sB2 = sC2; sB3 = sC3;
    }
  }
  for (; i < deg; i++) {
    int s0 = csrsrc[start + i];
    uint2 u0 = *(const uint2*)(xbase + (size_t)s0 * 2048);
    h2 xh0a = bits2h2(u0.x), xh0b = bits2h2(u0.y);
    h2 t0a = xh0a + xr0, t0b = xh0b + xr1;
    h2 r0a = __builtin_elementwise_max(t0a, t0a * ns);
    h2 r0b = __builtin_elementwise_max(t0b, t0b * ns);
    float p0 = __builtin_amdgcn_fdot2(r0b, aw1, __builtin_amdgcn_fdot2(r0a, aw0, 0.f, false), false);
    p0 = wred_add(p0);
    if (p0 > m) {
      float sc = exp2f(m - p0);
      floatx2 scv; scv.x = sc; scv.y = sc;
      accA *= scv; accB *= scv; l *= sc;
      m = p0;
    }
    float pe0 = exp2f(p0 - m);
    floatx2 x0A = h2f2(xh0a), x0B = h2f2(xh0b);
    floatx2 pe0v; pe0v.x = pe0; pe0v.y = pe0;
    accA += x0A * pe0v;
    accB += x0B * pe0v;
    l += pe0;
  }

  float rd = 1.f / (l + 1e-16f);
  float4 bv = *(const float4*)(bias + c);
  float o0 = accA.x * rd + bv.x, o1 = accA.y * rd + bv.y;
  float o2 = accB.x * rd + bv.z, o3 = accB.y * rd + bv.w;

  __shared__ float ws1[4], ws2[4];
  float s1 = o0 + o1 + o2 + o3;
  float s2 = o0 * o0 + o1 * o1 + o2 * o2 + o3 * o3;
#pragma unroll
  for (int mm = 32; mm >= 1; mm >>= 1) {
    s1 += __shfl_xor(s1, mm, 64);
    s2 += __shfl_xor(s2, mm, 64);
  }
  if (lane == 0) { ws1[wv] = s1; ws2[wv] = s2; }
  __syncthreads();
  float mean = (ws1[0] + ws1[1] + ws1[2] + ws1[3]) * (1.f / 1024.f);
  float var  = (ws2[0] + ws2[1] + ws2[2] + ws2[3]) * (1.f / 1024.f) - mean * mean;
  float rstd = rsqrtf(var + LN_EPS);
  float4 wv4 = *(const float4*)(lnw + c);
  float4 bb  = *(const float4*)(lnb + c);
  float z0 = (o0 - mean) * rstd * wv4.x + bb.x; z0 = z0 > 0.f ? z0 : expm1f(z0);
  float z1 = (o1 - mean) * rstd * wv4.y + bb.y; z1 = z1 > 0.f ? z1 : expm1f(z1);
  float z2 = (o2 - mean) * rstd * wv4.z + bb.z; z2 = z2 > 0.f ? z2 : expm1f(z2);
  float z3 = (o3 - mean) * rstd * wv4.w + bb.w; z3 = z3 > 0.f ? z3 : expm1f(z3);
  ushort4 u;
  u.x = f2bf(z0); u.y = f2bf(z1); u.z = f2bf(z2); u.w = f2bf(z3);
  *(ushort4*)(out + (size_t)d * 1024 + c) = u;
}

// ---------------- fused classifier: ELU(hb . wtc1 + b1) . w2 + b2 -> out --------
// R19: one kernel replaces {gemm_cls, cls2}. Phase 1: 128x256 GEMM, m97
// structure (A 4 slots + B 8 slots, proven XOR swizzle), acc[4][8]/wave
// (2M x 2N wave map). Phase 2: +bias, ELU, store h to LDS f16 [128][256] with
// chunk-XOR swizzle (kc ^= row&7, kills the 512B-stride bank conflict).
// Phase 3: 128x64 = h . wtc2^T via f16 MFMA (K=256, 64 MFMA/wave), w2t frags
// straight from global (32KB, L2-hot). Stores guarded j<49, node<N.

extern __shared__ unsigned short clssm[];   // 65536 B

__global__ __launch_bounds__(256) void cls_fused_kernel(
    const unsigned short* __restrict__ A,    // hb [MPAD][1024] bf16
    const unsigned short* __restrict__ Bt,   // wtc1 [256][1024] bf16
    const float* __restrict__ b1,            // [256]
    const unsigned short* __restrict__ w2t,  // wtc2 [64][256] f16 (zero-padded)
    const float* __restrict__ b2,            // [49]
    float* __restrict__ out)                 // [N][49]
{
  unsigned short* As = clssm;           // 128x64  (8192 ush, 16KB)
  unsigned short* Bs = clssm + 8192;    // 256x64  (16384 ush, 32KB)
  unsigned short* hbuf = clssm;         // reused: h [128][256] f16 (64KB)

  const int t = threadIdx.x;
  const int w = t >> 6, lane = t & 63;
  const int tile_m = blockIdx.x * 128;

  const int q = w * 64 + lane;          // 0..255
  const int row0 = q >> 3;              // 0..31
  const int gj = (q & 7) ^ (row0 & 7);
  const unsigned short* gA0 = A  + (size_t)(tile_m + row0) * 1024 + gj * 8;
  const unsigned short* gB0 = Bt + (size_t)row0 * 1024 + gj * 8;

  const int wm = (w >> 1) * 64, wn = (w & 1) * 128;
  const int lrow = lane & 15, cg0 = lane >> 4, sw = lrow & 7;

  floatx4 acc[4][8] = {};

#pragma unroll 1
  for (int k0 = 0; k0 < 1024; k0 += 64) {
#pragma unroll
    for (int p = 0; p < 4; p++)
      __builtin_amdgcn_global_load_lds(
          (const __attribute__((address_space(1))) void*)(gA0 + p * 32 * 1024),
          (__attribute__((address_space(3))) void*)(As + p * 2048 + w * 512), 16, 0, 0);
#pragma unroll
    for (int s = 0; s < 8; s++)
      __builtin_amdgcn_global_load_lds(
          (const __attribute__((address_space(1))) void*)(gB0 + s * 32 * 1024),
          (__attribute__((address_space(3))) void*)(Bs + s * 2048 + w * 512), 16, 0, 0);
    gA0 += 64; gB0 += 64;
    __syncthreads();
#pragma unroll
    for (int h = 0; h < 2; h++) {
      const int sc = ((h << 2) | cg0) ^ sw;
      bf16x8 a[4], b[8];
#pragma unroll
      for (int mi = 0; mi < 4; mi++) {
        int ar = wm + mi * 16 + lrow;
        a[mi] = *(const bf16x8*)(As + (ar >> 5) * 2048 + (ar & 31) * 64 + sc * 8);
      }
#pragma unroll
      for (int ni = 0; ni < 8; ni++) {
        int br = wn + ni * 16 + lrow;
        b[ni] = *(const bf16x8*)(Bs + (br >> 5) * 2048 + (br & 31) * 64 + sc * 8);
      }
#pragma unroll
      for (int mi = 0; mi < 4; mi++)
#pragma unroll
        for (int ni = 0; ni < 8; ni++)
          acc[mi][ni] = __builtin_amdgcn_mfma_f32_16x16x32_bf16(a[mi], b[ni], acc[mi][ni], 0, 0, 0);
    }
    __syncthreads();
  }

  // phase 2: bias + ELU -> hbuf (f16, chunk-XOR swizzled)
  float bcol[8];
#pragma unroll
  for (int ni = 0; ni < 8; ni++) bcol[ni] = b1[wn + ni * 16 + lrow];
  const int rbase = cg0 * 4;
#pragma unroll
  for (int mi = 0; mi < 4; mi++) {
#pragma unroll
    for (int r = 0; r < 4; r++) {
      int row = wm + mi * 16 + rbase + r;
#pragma unroll
      for (int ni = 0; ni < 8; ni++) {
        int col = wn + ni * 16 + lrow;
        float v = acc[mi][ni][r] + bcol[ni];
        v = v > 0.f ? v : expm1f(v);
        int kc = (col >> 3) ^ (row & 7);
        hbuf[row * 256 + kc * 8 + (col & 7)] = f2h(v);
      }
    }
  }
  __syncthreads();

  // phase 3: out[128][64] = h . w2t^T, f16 MFMA, K=256 (8 k-steps)
  floatx4 acc3[2][4] = {};
#pragma unroll
  for (int kst = 0; kst < 8; kst++) {
    h8 a3[2], b3[4];
#pragma unroll
    for (int mi = 0; mi < 2; mi++) {
      int ar = w * 32 + mi * 16 + lrow;
      int kc = (kst * 4 + cg0) ^ (ar & 7);
      a3[mi] = *(const h8*)(hbuf + ar * 256 + kc * 8);
    }
#pragma unroll
    for (int ni = 0; ni < 4; ni++) {
      int br = ni * 16 + lrow;
      b3[ni] = *(const h8*)(w2t + br * 256 + kst * 32 + cg0 * 8);
    }
#pragma unroll
    for (int mi = 0; mi < 2; mi++)
#pragma unroll
      for (int ni = 0; ni < 4; ni++)
        acc3[mi][ni] = __builtin_amdgcn_mfma_f32_16x16x32_f16(a3[mi], b3[ni], acc3[mi][ni], 0, 0, 0);
  }
#pragma unroll
  for (int mi = 0; mi < 2; mi++) {
    int rb = tile_m + w * 32 + mi * 16 + rbase;
#pragma unroll
    for (int r = 0; r < 4; r++) {
      int node = rb + r;
      if (node >= N_NODES) continue;
#pragma unroll
      for (int ni = 0; ni < 4; ni++) {
        int j = ni * 16 + lrow;
        if (j < OUT_CH) out[(size_t)node * OUT_CH + j] = acc3[mi][ni][r] + b2[j];
      }
    }
  }
}

// ---------------- launch ----------------

extern "C" void kernel_launch(void* const* d_in, const int* in_sizes, int n_in,
                              void* d_out, int out_size, void* d_ws, size_t ws_size,
                              hipStream_t stream)
{
  const float* x       = (const float*)d_in[0];
  const int*   ei      = (const int*)d_in[1];
  const float* c1_wl   = (const float*)d_in[2];
  const float* c1_bl   = (const float*)d_in[3];
  const float* c1_wr   = (const float*)d_in[4];
  const float* c1_br   = (const float*)d_in[5];
  const float* c1_att  = (const float*)d_in[6];
  const float* c1_bias = (const float*)d_in[7];
  const float* ln1_w   = (const float*)d_in[8];
  const float* ln1_b   = (const float*)d_in[9];
  const float* c2_wl   = (const float*)d_in[10];
  const float* c2_bl   = (const float*)d_in[11];
  const float* c2_wr   = (const float*)d_in[12];
  const float* c2_br   = (const float*)d_in[13];
  const float* c2_att  = (const float*)d_in[14];
  const float* c2_bias = (const float*)d_in[15];
  const float* ln2_w   = (const float*)d_in[16];
  const float* ln2_b   = (const float*)d_in[17];
  const float* cls_w1  = (const float*)d_in[18];
  const float* cls_b1  = (const float*)d_in[19];
  const float* cls_w2  = (const float*)d_in[20];
  const float* cls_b2  = (const float*)d_in[21];

  const int* srcArr = ei;
  const int* dstArr = ei + N_EDGES;

  char* ws = (char*)d_ws;
  size_t off = 0;
  auto alloc = [&](size_t bytes) { void* p = ws + off; off += (bytes + 255) & ~(size_t)255; return p; };
  unsigned short* xa      = (unsigned short*)alloc((size_t)MPAD * K1PAD * 2);
  unsigned short* wt1     = (unsigned short*)alloc((size_t)2048 * K1PAD * 2);
  unsigned short* wt2     = (unsigned short*)alloc((size_t)2048 * 1024 * 2);
  unsigned short* wtc1    = (unsigned short*)alloc((size_t)256 * 1024 * 2);
  unsigned short* wtc2    = (unsigned short*)alloc((size_t)64 * 256 * 2);
  unsigned short* xlr     = (unsigned short*)alloc((size_t)N_NODES * 2048 * 2);  // f16 xl|xr
  unsigned short* hb      = (unsigned short*)alloc((size_t)MPAD * 1024 * 2);
  int*            counts  = (int*)alloc(N_NODES * 4);
  int*            rwork   = (int*)alloc(N_NODES * 4);
  int*            rstart  = (int*)alloc((N_NODES + 1) * 4);
  int*            csrsrc  = (int*)alloc((E_TOT + 16) * 4);   // +16 prefetch pad
  (void)in_sizes; (void)n_in; (void)out_size; (void)ws_size;

  // prep (cast_x also zeroes counts — replaces memset)
  cast_x_kernel<<<(N_NODES * (K1PAD / 4) + 255) / 256, 256, 0, stream>>>(x, xa, counts);
  prep2_kernel<<<NB_W1 + NB_W2 + NB_WC + NB_WC2 + NB_CNT, 256, 0, stream>>>(
      c1_wl, c1_wr, c2_wl, c2_wr, cls_w1, cls_w2, dstArr, counts, wt1, wt2, wtc1, wtc2);

  // CSR by dst (payload = src node id)
  scan_kernel<<<1, 256, 0, stream>>>(counts, rstart, rwork);
  scatter_kernel<<<(E_TOT + 255) / 256, 256, 0, stream>>>(srcArr, dstArr, rwork, csrsrc);

  // layer 1
  gemm_bf16<2, K1PAD><<<dim3(16, 79), 256, 0, stream>>>(xa, wt1, nullptr, xlr, c1_bl, c1_br, N_NODES, 0, 1024);
  gat_ln_kernel<<<N_NODES, 256, 0, stream>>>(xlr, c1_att, csrsrc, rstart, c1_bias, ln1_w, ln1_b, hb);

  // layer 2
  gemm_bf16<2, 1024><<<dim3(16, 79), 256, 0, stream>>>(hb, wt2, nullptr, xlr, c2_bl, c2_br, N_NODES, 0, 1024);
  gat_ln_kernel<<<N_NODES, 256, 0, stream>>>(xlr, c2_att, csrsrc, rstart, c2_bias, ln2_w, ln2_b, hb);

  // classifier (fused: gemm + ELU + tiny f16-MFMA GEMM)
  cls_fused_kernel<<<79, 256, 65536, stream>>>(hb, wtc1, cls_b1, wtc2, cls_b2, (float*)d_out);
}